// Round 7
// baseline (581.672 us; speedup 1.0000x reference)
//
#include <hip/hip_runtime.h>
#include <hip/hip_bf16.h>

#define NB 32
#define NG 20
#define A_TOTAL 65472
#define LAB_OFF ((size_t)NB * A_TOTAL)   // floats
#define NW 16  // waves per 1024-thread block

__device__ __forceinline__ float b2f(unsigned short u) {
    __hip_bfloat16 h;
    __builtin_memcpy(&h, &u, 2);
    return __bfloat162float(h);
}

// f32 IoU, numpy/JAX op order, contraction off, IEEE div.
__device__ __forceinline__ float iou32(float a0, float a1, float a2, float a3,
                                       float g0, float g1, float g2, float g3) {
#pragma clang fp contract(off)
    float iw = fminf(a2, g2) - fmaxf(a0, g0) + 1.0f;
    iw = fmaxf(iw, 0.0f);
    float ih = fminf(a3, g3) - fmaxf(a1, g1) + 1.0f;
    ih = fmaxf(ih, 0.0f);
    float aa = (a2 - a0 + 1.0f) * (a3 - a1 + 1.0f);
    float ag = (g2 - g0 + 1.0f) * (g3 - g1 + 1.0f);
    float inter = iw * ih;
    return inter / (aa + ag - inter);
}

__device__ __forceinline__ float4 ldbox(const void* p, int idx, int isbf) {
    if (isbf) {
        const unsigned short* q = (const unsigned short*)p + (size_t)idx * 4;
        return make_float4(b2f(q[0]), b2f(q[1]), b2f(q[2]), b2f(q[3]));
    }
    return ((const float4*)p)[idx];
}

// One block per batch. No d_ws usage. Per-anchor (cls, argmax-g) codes staged
// as small floats in this batch's slice of the labels region of d_out, then
// overwritten with final f32 labels in phase 2. Forcing = single argmax
// anchor per gt at its best level (faithful JAX/np translation).
__global__ __launch_bounds__(1024)
void kFused(const void* __restrict__ bb, const void* __restrict__ idsv,
            const void* __restrict__ an0, const void* __restrict__ an1,
            const void* __restrict__ an2, const void* __restrict__ an3,
            const void* __restrict__ an4,
            float* __restrict__ out)
{
    __shared__ float sbox[NG][4];
    __shared__ float swv[NG][NW];
    __shared__ int   swi[NG][NW];
    __shared__ float lvv[NG][5];
    __shared__ int   lvi[NG][5];
    __shared__ float sid[NG];
    __shared__ int   sforce[NG];

    const int tid = threadIdx.x;
    const int b = blockIdx.x;

    // dtype detect: anchors_l0[0]=-18.6274, [2]=26.6274; bf16-decoding
    // ushort[0]/[2] only matches if the buffer really is bf16 (f32 low
    // mantissa halves decode to ~1e-36). Expect isbf=0 (f32 per template).
    const unsigned short* a0u = (const unsigned short*)an0;
    const int isbf = (fabsf(b2f(a0u[0]) + 18.6274f) < 0.5f &&
                      fabsf(b2f(a0u[2]) - 26.6274f) < 0.5f) ? 1 : 0;

    if (tid < NG * 4) {
        float v = isbf ? b2f(((const unsigned short*)bb)[b * NG * 4 + tid])
                       : ((const float*)bb)[b * NG * 4 + tid];
        sbox[tid >> 2][tid & 3] = v;
    }
    if (tid < NG) {
        // bird_ids: int32 (1..50) per template; tolerate f32 encoding.
        unsigned w = ((const unsigned*)idsv)[b * NG + tid];
        sid[tid] = (w <= 50u) ? (float)(int)w : __uint_as_float(w);
    }
    __syncthreads();

    const void* ans[5] = {an0, an1, an2, an3, an4};
    const int lcount[5] = {49152, 12288, 3072, 768, 192};
    const int loffs[5]  = {0, 49152, 61440, 64512, 65280};

    const int lane = tid & 63;
    const int wave = tid >> 6;
    float* myCodes = out + (size_t)b * A_TOTAL;  // this block's labels slice

    // ---- Phase 1: per-anchor codes + per-(gt,level) (max, min-index) ----
    for (int l = 0; l < 5; ++l) {
        float bv[NG];
        int bi[NG];
#pragma unroll
        for (int g = 0; g < NG; ++g) { bv[g] = -1.0f; bi[g] = 0x7fffffff; }
        const void* an = ans[l];
        const int cnt = lcount[l];

        for (int i = tid; i < cnt; i += 1024) {
            const float4 A = ldbox(an, i, isbf);
            float mx = -1.0f;
            int mg = 0;
#pragma unroll
            for (int g = 0; g < NG; ++g) {
                float v = iou32(A.x, A.y, A.z, A.w,
                                sbox[g][0], sbox[g][1], sbox[g][2], sbox[g][3]);
                if (v > mx) { mx = v; mg = g; }           // first-g wins (np.argmax)
                if (v > bv[g]) { bv[g] = v; bi[g] = i; }  // min index wins ties
            }
            const int cls = (mx >= 0.5f) ? 2 : (mx >= 0.4f) ? 1 : 0;
            myCodes[loffs[l] + i] = (float)(mg | (cls << 5));  // stage code
        }

#pragma unroll
        for (int g = 0; g < NG; ++g) {
            float v = bv[g];
            int ix = bi[g];
            for (int o = 32; o > 0; o >>= 1) {
                float ov = __shfl_xor(v, o);
                int   oi = __shfl_xor(ix, o);
                if (ov > v || (ov == v && oi < ix)) { v = ov; ix = oi; }
            }
            if (lane == 0) { swv[g][wave] = v; swi[g][wave] = ix; }
        }
        __syncthreads();
        if (tid < NG) {
            float v = swv[tid][0];
            int ix = swi[tid][0];
            for (int w = 1; w < NW; ++w) {
                float ov = swv[tid][w];
                int   oi = swi[tid][w];
                if (ov > v || (ov == v && oi < ix)) { v = ov; ix = oi; }
            }
            lvv[tid][l] = v;
            lvi[tid][l] = ix;   // level-local index
        }
        __syncthreads();   // protects swv reuse next level
    }

    if (tid < NG) {
        int bl = 0;   // level argmax: strict > keeps first level (np.argmax)
#pragma unroll
        for (int l = 1; l < 5; ++l)
            if (lvv[tid][l] > lvv[tid][bl]) bl = l;
        sforce[tid] = loffs[bl] + lvi[tid][bl];   // forced global anchor index
    }
    __syncthreads();   // codes (block-local global) + sforce visible

    // ---- Phase 2: finalize f32 labels + f32 reg ----
    float4* rp = (float4*)(out + LAB_OFF);
    for (int a = tid; a < A_TOTAL; a += 1024) {
        int l, off;
        if (a < 49152)      { l = 0; off = 0; }
        else if (a < 61440) { l = 1; off = 49152; }
        else if (a < 64512) { l = 2; off = 61440; }
        else if (a < 65280) { l = 3; off = 64512; }
        else                { l = 4; off = 65280; }

        const int code = (int)myCodes[a];
        const int mg = code & 31;
        const int cls = code >> 5;

        // forced matches: last g wins == np scatter last-write-wins
        int fg = -1;
#pragma unroll
        for (int g = 0; g < NG; ++g)
            if (sforce[g] == a) fg = g;

        const bool pos = (cls == 2) || (fg >= 0);
        const bool ign = (cls == 1);
        const int ug = (fg >= 0) ? fg : mg;

        myCodes[a] = pos ? sid[ug] : (ign ? -1.0f : 0.0f);  // final f32 label

        float t0 = 0.f, t1 = 0.f, t2 = 0.f, t3 = 0.f;
        if (pos) {
#pragma clang fp contract(off)
            const float4 A = ldbox(ans[l], a - off, isbf);
            const float ew = A.z - A.x + 1.0f, eh = A.w - A.y + 1.0f;
            const float ecx = A.x + 0.5f * ew, ecy = A.y + 0.5f * eh;
            const float g0 = sbox[ug][0], g1 = sbox[ug][1];
            const float g2 = sbox[ug][2], g3 = sbox[ug][3];
            const float gw = g2 - g0 + 1.0f, gh = g3 - g1 + 1.0f;
            const float gcx = g0 + 0.5f * gw, gcy = g1 + 0.5f * gh;
            t0 = (gcx - ecx) / ew;
            t1 = (gcy - ecy) / eh;
            t2 = logf(gw / ew);
            t3 = logf(gh / eh);
        }
        rp[(size_t)b * A_TOTAL + a] = make_float4(t0, t1, t2, t3);
    }
}

extern "C" void kernel_launch(void* const* d_in, const int* in_sizes, int n_in,
                              void* d_out, int out_size, void* d_ws, size_t ws_size,
                              hipStream_t stream) {
    // Map inputs by element count (all distinct) instead of trusting order.
    const void* bb = d_in[0];
    const void* ids = d_in[1];
    const void* an[5] = {d_in[2], d_in[3], d_in[4], d_in[5], d_in[6]};
    if (n_in == 7) {
        for (int i = 0; i < 7; ++i) {
            switch (in_sizes[i]) {
                case 2560:   bb    = d_in[i]; break;
                case 640:    ids   = d_in[i]; break;
                case 196608: an[0] = d_in[i]; break;
                case 49152:  an[1] = d_in[i]; break;
                case 12288:  an[2] = d_in[i]; break;
                case 3072:   an[3] = d_in[i]; break;
                case 768:    an[4] = d_in[i]; break;
                default: break;
            }
        }
    }
    hipLaunchKernelGGL(kFused, dim3(NB), dim3(1024), 0, stream,
                       bb, ids, an[0], an[1], an[2], an[3], an[4],
                       (float*)d_out);
}

// Round 8
// 188.299 us; speedup vs baseline: 3.0891x; 3.0891x over previous
//
#include <hip/hip_runtime.h>
#include <hip/hip_bf16.h>

#define NB 32
#define NG 20
#define A_TOTAL 65472
#define LAB_OFF ((size_t)NB * A_TOTAL)   // floats
#define NCH 65                            // 1024-anchor, level-aligned chunks

__device__ __forceinline__ float b2f(unsigned short u) {
    __hip_bfloat16 h;
    __builtin_memcpy(&h, &u, 2);
    return __bfloat162float(h);
}

// f32 IoU, numpy/JAX op order, contraction off, IEEE div.
__device__ __forceinline__ float iou32(float a0, float a1, float a2, float a3,
                                       float g0, float g1, float g2, float g3) {
#pragma clang fp contract(off)
    float iw = fminf(a2, g2) - fmaxf(a0, g0) + 1.0f;
    iw = fmaxf(iw, 0.0f);
    float ih = fminf(a3, g3) - fmaxf(a1, g1) + 1.0f;
    ih = fmaxf(ih, 0.0f);
    float aa = (a2 - a0 + 1.0f) * (a3 - a1 + 1.0f);
    float ag = (g2 - g0 + 1.0f) * (g3 - g1 + 1.0f);
    float inter = iw * ih;
    return inter / (aa + ag - inter);
}

__device__ __forceinline__ float4 ldbox(const void* p, int idx, int isbf) {
    if (isbf) {
        const unsigned short* q = (const unsigned short*)p + (size_t)idx * 4;
        return make_float4(b2f(q[0]), b2f(q[1]), b2f(q[2]), b2f(q[3]));
    }
    return ((const float4*)p)[idx];
}

__device__ __forceinline__ int detect_bf(const void* an0) {
    const unsigned short* u = (const unsigned short*)an0;
    return (fabsf(b2f(u[0]) + 18.6274f) < 0.5f &&
            fabsf(b2f(u[2]) - 26.6274f) < 0.5f) ? 1 : 0;
}

__device__ __forceinline__ float decode_id(const void* idsv, int i) {
    unsigned w = ((const unsigned*)idsv)[i];
    return (w <= 50u) ? (float)(int)w : __uint_as_float(w);
}

__device__ __forceinline__ void reg_transform(float4 A, float g0, float g1,
                                              float g2, float g3,
                                              float& t0, float& t1,
                                              float& t2, float& t3) {
#pragma clang fp contract(off)
    const float ew = A.z - A.x + 1.0f, eh = A.w - A.y + 1.0f;
    const float ecx = A.x + 0.5f * ew, ecy = A.y + 0.5f * eh;
    const float gw = g2 - g0 + 1.0f, gh = g3 - g1 + 1.0f;
    const float gcx = g0 + 0.5f * gw, gcy = g1 + 0.5f * gh;
    t0 = (gcx - ecx) / ew;
    t1 = (gcy - ecy) / eh;
    t2 = logf(gw / ew);
    t3 = logf(gh / eh);
}

// ---- Kernel 1: per-anchor final (unforced) labels+reg + per-(b,g,chunk)
// best-IoU partials. Grid (NCH, NB) x 256; 4 anchors/thread.
__global__ __launch_bounds__(256)
void kCodes(const void* __restrict__ bb, const void* __restrict__ idsv,
            const void* __restrict__ an0, const void* __restrict__ an1,
            const void* __restrict__ an2, const void* __restrict__ an3,
            const void* __restrict__ an4,
            float* __restrict__ out,
            float* __restrict__ part_v, int* __restrict__ part_i)
{
    __shared__ float sbox[NG][4];
    __shared__ float sid[NG];
    __shared__ float swv[NG][4];
    __shared__ int   swi[NG][4];

    const int tid = threadIdx.x;
    const int b = blockIdx.y;
    const int c = blockIdx.x;
    const int isbf = detect_bf(an0);

    if (tid < NG * 4) {
        float v = isbf ? b2f(((const unsigned short*)bb)[b * NG * 4 + tid])
                       : ((const float*)bb)[b * NG * 4 + tid];
        sbox[tid >> 2][tid & 3] = v;
    }
    if (tid >= 128 && tid < 128 + NG)
        sid[tid - 128] = decode_id(idsv, b * NG + (tid - 128));
    __syncthreads();

    int l, lbase, count, goff;
    if (c < 48)      { l = 0; lbase = c * 1024;        count = 1024; goff = 0; }
    else if (c < 60) { l = 1; lbase = (c - 48) * 1024; count = 1024; goff = 49152; }
    else if (c < 63) { l = 2; lbase = (c - 60) * 1024; count = 1024; goff = 61440; }
    else if (c == 63){ l = 3; lbase = 0;               count = 768;  goff = 64512; }
    else             { l = 4; lbase = 0;               count = 192;  goff = 65280; }
    const void* an = (l == 0) ? an0 : (l == 1) ? an1
                   : (l == 2) ? an2 : (l == 3) ? an3 : an4;

    float bv[NG];
    int bi[NG];
#pragma unroll
    for (int g = 0; g < NG; ++g) { bv[g] = -1.0f; bi[g] = 0x7fffffff; }

    float* lab = out + (size_t)b * A_TOTAL;
    float4* rp = (float4*)(out + LAB_OFF) + (size_t)b * A_TOTAL;

    for (int k = 0; k < 4; ++k) {
        const int i = tid + k * 256;
        if (i < count) {
            const int local = lbase + i;
            const int ga = goff + local;
            const float4 A = ldbox(an, local, isbf);
            float mx = -1.0f;
            int mg = 0;
#pragma unroll
            for (int g = 0; g < NG; ++g) {
                float v = iou32(A.x, A.y, A.z, A.w,
                                sbox[g][0], sbox[g][1], sbox[g][2], sbox[g][3]);
                if (v > mx) { mx = v; mg = g; }             // first-g wins (np.argmax)
                if (v > bv[g]) { bv[g] = v; bi[g] = ga; }   // min global idx on ties
            }
            const bool pos = (mx >= 0.5f);
            lab[ga] = pos ? sid[mg] : ((mx >= 0.4f) ? -1.0f : 0.0f);
            float t0 = 0.f, t1 = 0.f, t2 = 0.f, t3 = 0.f;
            if (pos)
                reg_transform(A, sbox[mg][0], sbox[mg][1], sbox[mg][2], sbox[mg][3],
                              t0, t1, t2, t3);
            rp[ga] = make_float4(t0, t1, t2, t3);
        }
    }

    const int lane = tid & 63;
    const int wave = tid >> 6;
#pragma unroll
    for (int g = 0; g < NG; ++g) {
        float v = bv[g];
        int ix = bi[g];
        for (int o = 32; o > 0; o >>= 1) {
            float ov = __shfl_xor(v, o);
            int   oi = __shfl_xor(ix, o);
            if (ov > v || (ov == v && oi < ix)) { v = ov; ix = oi; }
        }
        if (lane == 0) { swv[g][wave] = v; swi[g][wave] = ix; }
    }
    __syncthreads();
    if (tid < NG) {
        float v = swv[tid][0];
        int ix = swi[tid][0];
        for (int w = 1; w < 4; ++w) {
            float ov = swv[tid][w];
            int   oi = swi[tid][w];
            if (ov > v || (ov == v && oi < ix)) { v = ov; ix = oi; }
        }
        part_v[(b * NG + tid) * NCH + c] = v;
        part_i[(b * NG + tid) * NCH + c] = ix;   // global anchor index
    }
}

// ---- Kernel 2: reduce partials -> forced anchor per (b,g); patch <=20
// labels+regs per batch. Grid NB x 64.
__global__ __launch_bounds__(64)
void kForce(const void* __restrict__ bb, const void* __restrict__ idsv,
            const void* __restrict__ an0, const void* __restrict__ an1,
            const void* __restrict__ an2, const void* __restrict__ an3,
            const void* __restrict__ an4,
            const float* __restrict__ part_v, const int* __restrict__ part_i,
            float* __restrict__ out)
{
    __shared__ int sforce[NG];
    const int b = blockIdx.x;
    const int g = threadIdx.x;
    const int isbf = detect_bf(an0);

    if (g < NG) {
        float Lv[5];
        int Li[5];
#pragma unroll
        for (int l = 0; l < 5; ++l) { Lv[l] = -2.0f; Li[l] = 0x7fffffff; }
        for (int c = 0; c < NCH; ++c) {
            const int l = (c < 48) ? 0 : (c < 60) ? 1 : (c < 63) ? 2 : (c == 63) ? 3 : 4;
            const float v = part_v[(b * NG + g) * NCH + c];
            const int   i = part_i[(b * NG + g) * NCH + c];
            if (v > Lv[l] || (v == Lv[l] && i < Li[l])) { Lv[l] = v; Li[l] = i; }
        }
        int bl = 0;   // level argmax: strict > keeps first level (np.argmax)
#pragma unroll
        for (int l = 1; l < 5; ++l)
            if (Lv[l] > Lv[bl]) bl = l;
        sforce[g] = Li[bl];
    }
    __syncthreads();

    if (g < NG) {
        const int a = sforce[g];
        bool win = true;   // last-g-wins == np scatter last-write-wins
        for (int g2 = g + 1; g2 < NG; ++g2)
            if (sforce[g2] == a) win = false;
        if (win) {
            int l, off;
            if (a < 49152)      { l = 0; off = 0; }
            else if (a < 61440) { l = 1; off = 49152; }
            else if (a < 64512) { l = 2; off = 61440; }
            else if (a < 65280) { l = 3; off = 64512; }
            else                { l = 4; off = 65280; }
            const void* an = (l == 0) ? an0 : (l == 1) ? an1
                           : (l == 2) ? an2 : (l == 3) ? an3 : an4;
            const float4 A = ldbox(an, a - off, isbf);
            float g0, g1, g2b, g3;
            if (isbf) {
                const unsigned short* q = (const unsigned short*)bb + (b * NG + g) * 4;
                g0 = b2f(q[0]); g1 = b2f(q[1]); g2b = b2f(q[2]); g3 = b2f(q[3]);
            } else {
                const float4 G = ((const float4*)bb)[b * NG + g];
                g0 = G.x; g1 = G.y; g2b = G.z; g3 = G.w;
            }
            out[(size_t)b * A_TOTAL + a] = decode_id(idsv, b * NG + g);
            float t0, t1, t2, t3;
            reg_transform(A, g0, g1, g2b, g3, t0, t1, t2, t3);
            ((float4*)(out + LAB_OFF))[(size_t)b * A_TOTAL + a]
                = make_float4(t0, t1, t2, t3);
        }
    }
}

// ---------- Fallback (round-7 passing kernel): used only if ws too small ----
__global__ __launch_bounds__(1024)
void kFused(const void* __restrict__ bb, const void* __restrict__ idsv,
            const void* __restrict__ an0, const void* __restrict__ an1,
            const void* __restrict__ an2, const void* __restrict__ an3,
            const void* __restrict__ an4,
            float* __restrict__ out)
{
    __shared__ float sbox[NG][4];
    __shared__ float swv[NG][16];
    __shared__ int   swi[NG][16];
    __shared__ float lvv[NG][5];
    __shared__ int   lvi[NG][5];
    __shared__ float sid[NG];
    __shared__ int   sforce[NG];

    const int tid = threadIdx.x;
    const int b = blockIdx.x;
    const int isbf = detect_bf(an0);

    if (tid < NG * 4) {
        float v = isbf ? b2f(((const unsigned short*)bb)[b * NG * 4 + tid])
                       : ((const float*)bb)[b * NG * 4 + tid];
        sbox[tid >> 2][tid & 3] = v;
    }
    if (tid < NG) sid[tid] = decode_id(idsv, b * NG + tid);
    __syncthreads();

    const void* ans[5] = {an0, an1, an2, an3, an4};
    const int lcount[5] = {49152, 12288, 3072, 768, 192};
    const int loffs[5]  = {0, 49152, 61440, 64512, 65280};
    const int lane = tid & 63;
    const int wave = tid >> 6;
    float* myCodes = out + (size_t)b * A_TOTAL;

    for (int l = 0; l < 5; ++l) {
        float bv[NG];
        int bi[NG];
#pragma unroll
        for (int g = 0; g < NG; ++g) { bv[g] = -1.0f; bi[g] = 0x7fffffff; }
        for (int i = tid; i < lcount[l]; i += 1024) {
            const float4 A = ldbox(ans[l], i, isbf);
            float mx = -1.0f;
            int mg = 0;
#pragma unroll
            for (int g = 0; g < NG; ++g) {
                float v = iou32(A.x, A.y, A.z, A.w,
                                sbox[g][0], sbox[g][1], sbox[g][2], sbox[g][3]);
                if (v > mx) { mx = v; mg = g; }
                if (v > bv[g]) { bv[g] = v; bi[g] = i; }
            }
            const int cls = (mx >= 0.5f) ? 2 : (mx >= 0.4f) ? 1 : 0;
            myCodes[loffs[l] + i] = (float)(mg | (cls << 5));
        }
#pragma unroll
        for (int g = 0; g < NG; ++g) {
            float v = bv[g];
            int ix = bi[g];
            for (int o = 32; o > 0; o >>= 1) {
                float ov = __shfl_xor(v, o);
                int   oi = __shfl_xor(ix, o);
                if (ov > v || (ov == v && oi < ix)) { v = ov; ix = oi; }
            }
            if (lane == 0) { swv[g][wave] = v; swi[g][wave] = ix; }
        }
        __syncthreads();
        if (tid < NG) {
            float v = swv[tid][0];
            int ix = swi[tid][0];
            for (int w = 1; w < 16; ++w) {
                float ov = swv[tid][w];
                int   oi = swi[tid][w];
                if (ov > v || (ov == v && oi < ix)) { v = ov; ix = oi; }
            }
            lvv[tid][l] = v;
            lvi[tid][l] = ix;
        }
        __syncthreads();
    }
    if (tid < NG) {
        int bl = 0;
#pragma unroll
        for (int l = 1; l < 5; ++l)
            if (lvv[tid][l] > lvv[tid][bl]) bl = l;
        sforce[tid] = loffs[bl] + lvi[tid][bl];
    }
    __syncthreads();

    float4* rp = (float4*)(out + LAB_OFF);
    for (int a = tid; a < A_TOTAL; a += 1024) {
        int l, off;
        if (a < 49152)      { l = 0; off = 0; }
        else if (a < 61440) { l = 1; off = 49152; }
        else if (a < 64512) { l = 2; off = 61440; }
        else if (a < 65280) { l = 3; off = 64512; }
        else                { l = 4; off = 65280; }
        const int code = (int)myCodes[a];
        const int mg = code & 31;
        const int cls = code >> 5;
        int fg = -1;
#pragma unroll
        for (int g = 0; g < NG; ++g)
            if (sforce[g] == a) fg = g;
        const bool pos = (cls == 2) || (fg >= 0);
        const int ug = (fg >= 0) ? fg : mg;
        myCodes[a] = pos ? sid[ug] : ((cls == 1) ? -1.0f : 0.0f);
        float t0 = 0.f, t1 = 0.f, t2 = 0.f, t3 = 0.f;
        if (pos) {
            const float4 A = ldbox(ans[l], a - off, isbf);
            reg_transform(A, sbox[ug][0], sbox[ug][1], sbox[ug][2], sbox[ug][3],
                          t0, t1, t2, t3);
        }
        rp[(size_t)b * A_TOTAL + a] = make_float4(t0, t1, t2, t3);
    }
}

extern "C" void kernel_launch(void* const* d_in, const int* in_sizes, int n_in,
                              void* d_out, int out_size, void* d_ws, size_t ws_size,
                              hipStream_t stream) {
    const void* bb = d_in[0];
    const void* ids = d_in[1];
    const void* an[5] = {d_in[2], d_in[3], d_in[4], d_in[5], d_in[6]};
    if (n_in == 7) {
        for (int i = 0; i < 7; ++i) {
            switch (in_sizes[i]) {
                case 2560:   bb    = d_in[i]; break;
                case 640:    ids   = d_in[i]; break;
                case 196608: an[0] = d_in[i]; break;
                case 49152:  an[1] = d_in[i]; break;
                case 12288:  an[2] = d_in[i]; break;
                case 3072:   an[3] = d_in[i]; break;
                case 768:    an[4] = d_in[i]; break;
                default: break;
            }
        }
    }
    float* out = (float*)d_out;
    const size_t nPart = (size_t)NB * NG * NCH;           // 41600
    const size_t need = nPart * (sizeof(float) + sizeof(int));  // 332800 B

    if (ws_size >= need) {
        float* part_v = (float*)d_ws;
        int*   part_i = (int*)((char*)d_ws + nPart * sizeof(float));
        hipLaunchKernelGGL(kCodes, dim3(NCH, NB), dim3(256), 0, stream,
                           bb, ids, an[0], an[1], an[2], an[3], an[4],
                           out, part_v, part_i);
        hipLaunchKernelGGL(kForce, dim3(NB), dim3(64), 0, stream,
                           bb, ids, an[0], an[1], an[2], an[3], an[4],
                           part_v, part_i, out);
    } else {
        hipLaunchKernelGGL(kFused, dim3(NB), dim3(1024), 0, stream,
                           bb, ids, an[0], an[1], an[2], an[3], an[4], out);
    }
}

// Round 10
// 130.032 us; speedup vs baseline: 4.4733x; 1.4481x over previous
//
#include <hip/hip_runtime.h>
#include <hip/hip_bf16.h>

#define NB 32
#define NG 20
#define A_TOTAL 65472
#define LAB_OFF ((size_t)NB * A_TOTAL)   // floats
#define NSLOT (NB * NG * 5)              // (b,g,level) u64 slots

__device__ __forceinline__ float b2f(unsigned short u) {
    __hip_bfloat16 h;
    __builtin_memcpy(&h, &u, 2);
    return __bfloat162float(h);
}

__device__ __forceinline__ float4 ldbox(const void* p, int idx, int isbf) {
    if (isbf) {
        const unsigned short* q = (const unsigned short*)p + (size_t)idx * 4;
        return make_float4(b2f(q[0]), b2f(q[1]), b2f(q[2]), b2f(q[3]));
    }
    return ((const float4*)p)[idx];
}

__device__ __forceinline__ int detect_bf(const void* an0) {
    const unsigned short* u = (const unsigned short*)an0;
    return (fabsf(b2f(u[0]) + 18.6274f) < 0.5f &&
            fabsf(b2f(u[2]) - 26.6274f) < 0.5f) ? 1 : 0;
}

__device__ __forceinline__ float decode_id(const void* idsv, int i) {
    unsigned w = ((const unsigned*)idsv)[i];
    return (w <= 50u) ? (float)(int)w : __uint_as_float(w);
}

// (x2-x0+1)*(x3-x1+1), contract-off so bits match the numpy reference.
__device__ __forceinline__ float area1(float4 A) {
#pragma clang fp contract(off)
    return (A.z - A.x + 1.0f) * (A.w - A.y + 1.0f);
}

__device__ __forceinline__ void reg_transform(float4 A, float g0, float g1,
                                              float g2, float g3,
                                              float& t0, float& t1,
                                              float& t2, float& t3) {
#pragma clang fp contract(off)
    const float ew = A.z - A.x + 1.0f, eh = A.w - A.y + 1.0f;
    const float ecx = A.x + 0.5f * ew, ecy = A.y + 0.5f * eh;
    const float gw = g2 - g0 + 1.0f, gh = g3 - g1 + 1.0f;
    const float gcx = g0 + 0.5f * gw, gcy = g1 + 0.5f * gh;
    t0 = (gcx - ecx) / ew;
    t1 = (gcy - ecy) / eh;
    t2 = logf(gw / ew);
    t3 = logf(gh / eh);
}

// f32 IoU, identical op order / rounding to the r8 passing kernel.
__device__ __forceinline__ float iou32h(float4 A, float aa,
                                        float4 G, float ag) {
#pragma clang fp contract(off)
    float iw = fminf(A.z, G.z) - fmaxf(A.x, G.x) + 1.0f;
    iw = fmaxf(iw, 0.0f);
    float ih = fminf(A.w, G.w) - fmaxf(A.y, G.y) + 1.0f;
    ih = fmaxf(ih, 0.0f);
    float inter = iw * ih;
    return inter / (aa + ag - inter);
}

// ---- Kernel 1: per-anchor final (unforced) labels+reg, plus per-(b,g,level)
// best via packed-u64 atomicMax. Grid (65, NB) x 256; 4 anchors/thread.
__global__ __launch_bounds__(256, 6)
void kCodes(const void* __restrict__ bb, const void* __restrict__ idsv,
            const void* __restrict__ an0, const void* __restrict__ an1,
            const void* __restrict__ an2, const void* __restrict__ an3,
            const void* __restrict__ an4,
            float* __restrict__ out,
            unsigned long long* __restrict__ slots)
{
    __shared__ float4 sbox4[NG];
    __shared__ float  sid[NG];
    __shared__ unsigned long long swk[NG][4];

    const int tid = threadIdx.x;
    const int b = blockIdx.y;
    const int c = blockIdx.x;
    const int isbf = detect_bf(an0);

    if (tid < NG) {
        sbox4[tid] = ldbox(bb, b * NG + tid, isbf);
        sid[tid] = decode_id(idsv, b * NG + tid);
    }
    __syncthreads();

    int l, lbase, count, goff;
    if (c < 48)      { l = 0; lbase = c * 1024;        count = 1024; goff = 0; }
    else if (c < 60) { l = 1; lbase = (c - 48) * 1024; count = 1024; goff = 49152; }
    else if (c < 63) { l = 2; lbase = (c - 60) * 1024; count = 1024; goff = 61440; }
    else if (c == 63){ l = 3; lbase = 0;               count = 768;  goff = 64512; }
    else             { l = 4; lbase = 0;               count = 192;  goff = 65280; }
    const void* an = (l == 0) ? an0 : (l == 1) ? an1
                   : (l == 2) ? an2 : (l == 3) ? an3 : an4;

    // Anchors in registers; invalid lanes get a far-away dummy (IoU = 0).
    float4 A[4];
    float aa[4];
    bool val[4];
#pragma unroll
    for (int k = 0; k < 4; ++k) {
        const int i = tid + k * 256;
        val[k] = (i < count);
        A[k] = val[k] ? ldbox(an, lbase + i, isbf)
                      : make_float4(-1e8f, -1e8f, -1e8f, -1e8f);
        aa[k] = area1(A[k]);
    }

    float mx[4] = {-1.f, -1.f, -1.f, -1.f};
    int mg[4] = {0, 0, 0, 0};
    const int lane = tid & 63;
    const int wave = tid >> 6;

    for (int g = 0; g < NG; ++g) {
        const float4 G = sbox4[g];
        const float ag = area1(G);
        float bvv = -1.0f;
        int bii = 0;
#pragma unroll
        for (int k = 0; k < 4; ++k) {
            const float v = iou32h(A[k], aa[k], G, ag);
            if (v > mx[k]) { mx[k] = v; mg[k] = g; }   // first-g wins (np.argmax)
            if (v > bvv)   { bvv = v; bii = goff + lbase + tid + k * 256; }
        }
        // pack (value, min-index) so u64 max == (max IoU, lowest idx on tie)
        unsigned long long key =
            ((unsigned long long)__float_as_uint(bvv) << 32)
            | (unsigned)(~(unsigned)bii);
        for (int o = 32; o > 0; o >>= 1) {
            const unsigned long long ok = __shfl_xor(key, o);
            if (ok > key) key = ok;
        }
        if (lane == 0) swk[g][wave] = key;
    }

    // final (unforced) labels + reg
    float* lab = out + (size_t)b * A_TOTAL;
    float4* rp = (float4*)(out + LAB_OFF) + (size_t)b * A_TOTAL;
#pragma unroll
    for (int k = 0; k < 4; ++k) {
        if (!val[k]) continue;
        const int ga = goff + lbase + tid + k * 256;
        const bool pos = (mx[k] >= 0.5f);
        lab[ga] = pos ? sid[mg[k]] : ((mx[k] >= 0.4f) ? -1.0f : 0.0f);
        float t0 = 0.f, t1 = 0.f, t2 = 0.f, t3 = 0.f;
        if (pos) {
            const float4 G = sbox4[mg[k]];
            reg_transform(A[k], G.x, G.y, G.z, G.w, t0, t1, t2, t3);
        }
        rp[ga] = make_float4(t0, t1, t2, t3);
    }

    __syncthreads();
    if (tid < NG) {
        unsigned long long k0 = swk[tid][0];
        for (int w = 1; w < 4; ++w)
            if (swk[tid][w] > k0) k0 = swk[tid][w];
        atomicMax(&slots[(b * NG + tid) * 5 + l], k0);
    }
}

// ---- Kernel 2: per-(b,g) level argmax (first-level wins) -> forced anchor;
// dedup last-g-wins; patch <=20 labels+regs per batch. Grid NB x 64.
__global__ __launch_bounds__(64)
void kForce(const void* __restrict__ bb, const void* __restrict__ idsv,
            const void* __restrict__ an0, const void* __restrict__ an1,
            const void* __restrict__ an2, const void* __restrict__ an3,
            const void* __restrict__ an4,
            const unsigned long long* __restrict__ slots,
            float* __restrict__ out)
{
    __shared__ int sforce[NG];
    const int b = blockIdx.x;
    const int g = threadIdx.x;
    const int isbf = detect_bf(an0);

    if (g < NG) {
        const unsigned long long* s = &slots[(b * NG + g) * 5];
        unsigned long long best = s[0];
        for (int l = 1; l < 5; ++l) {
            // compare IoU bits only (nonneg f32 -> monotone as uint);
            // strict > keeps the first level (np.argmax over levels)
            if ((unsigned)(s[l] >> 32) > (unsigned)(best >> 32)) best = s[l];
        }
        sforce[g] = (int)(~(unsigned)best);   // global anchor index
    }
    __syncthreads();

    if (g < NG) {
        const int a = sforce[g];
        bool win = true;   // last-g-wins == np scatter last-write-wins
        for (int g2 = g + 1; g2 < NG; ++g2)
            if (sforce[g2] == a) win = false;
        if (win) {
            int l, off;
            if (a < 49152)      { l = 0; off = 0; }
            else if (a < 61440) { l = 1; off = 49152; }
            else if (a < 64512) { l = 2; off = 61440; }
            else if (a < 65280) { l = 3; off = 64512; }
            else                { l = 4; off = 65280; }
            const void* an = (l == 0) ? an0 : (l == 1) ? an1
                           : (l == 2) ? an2 : (l == 3) ? an3 : an4;
            const float4 A = ldbox(an, a - off, isbf);
            const float4 G = ldbox(bb, b * NG + g, isbf);
            out[(size_t)b * A_TOTAL + a] = decode_id(idsv, b * NG + g);
            float t0, t1, t2, t3;
            reg_transform(A, G.x, G.y, G.z, G.w, t0, t1, t2, t3);
            ((float4*)(out + LAB_OFF))[(size_t)b * A_TOTAL + a]
                = make_float4(t0, t1, t2, t3);
        }
    }
}

// ---------- Fallback (round-7 passing kernel): used only if ws too small ----
__global__ __launch_bounds__(1024)
void kFused(const void* __restrict__ bb, const void* __restrict__ idsv,
            const void* __restrict__ an0, const void* __restrict__ an1,
            const void* __restrict__ an2, const void* __restrict__ an3,
            const void* __restrict__ an4,
            float* __restrict__ out)
{
    __shared__ float4 sbox4[NG];
    __shared__ float swv[NG][16];
    __shared__ int   swi[NG][16];
    __shared__ float lvv[NG][5];
    __shared__ int   lvi[NG][5];
    __shared__ float sid[NG];
    __shared__ int   sforce[NG];

    const int tid = threadIdx.x;
    const int b = blockIdx.x;
    const int isbf = detect_bf(an0);

    if (tid < NG) {
        sbox4[tid] = ldbox(bb, b * NG + tid, isbf);
        sid[tid] = decode_id(idsv, b * NG + tid);
    }
    __syncthreads();

    const void* ans[5] = {an0, an1, an2, an3, an4};
    const int lcount[5] = {49152, 12288, 3072, 768, 192};
    const int loffs[5]  = {0, 49152, 61440, 64512, 65280};
    const int lane = tid & 63;
    const int wave = tid >> 6;
    float* myCodes = out + (size_t)b * A_TOTAL;

    for (int l = 0; l < 5; ++l) {
        float bv[NG];
        int bi[NG];
#pragma unroll
        for (int g = 0; g < NG; ++g) { bv[g] = -1.0f; bi[g] = 0x7fffffff; }
        for (int i = tid; i < lcount[l]; i += 1024) {
            const float4 A = ldbox(ans[l], i, isbf);
            const float aa = area1(A);
            float mxv = -1.0f;
            int mgv = 0;
#pragma unroll
            for (int g = 0; g < NG; ++g) {
                const float4 G = sbox4[g];
                const float ag = area1(G);
                float v = iou32h(A, aa, G, ag);
                if (v > mxv) { mxv = v; mgv = g; }
                if (v > bv[g]) { bv[g] = v; bi[g] = i; }
            }
            const int cls = (mxv >= 0.5f) ? 2 : (mxv >= 0.4f) ? 1 : 0;
            myCodes[loffs[l] + i] = (float)(mgv | (cls << 5));
        }
#pragma unroll
        for (int g = 0; g < NG; ++g) {
            float v = bv[g];
            int ix = bi[g];
            for (int o = 32; o > 0; o >>= 1) {
                float ov = __shfl_xor(v, o);
                int   oi = __shfl_xor(ix, o);
                if (ov > v || (ov == v && oi < ix)) { v = ov; ix = oi; }
            }
            if (lane == 0) { swv[g][wave] = v; swi[g][wave] = ix; }
        }
        __syncthreads();
        if (tid < NG) {
            float v = swv[tid][0];
            int ix = swi[tid][0];
            for (int w = 1; w < 16; ++w) {
                float ov = swv[tid][w];
                int   oi = swi[tid][w];
                if (ov > v || (ov == v && oi < ix)) { v = ov; ix = oi; }
            }
            lvv[tid][l] = v;
            lvi[tid][l] = ix;
        }
        __syncthreads();
    }
    if (tid < NG) {
        int bl = 0;
#pragma unroll
        for (int l = 1; l < 5; ++l)
            if (lvv[tid][l] > lvv[tid][bl]) bl = l;
        sforce[tid] = loffs[bl] + lvi[tid][bl];
    }
    __syncthreads();

    float4* rp = (float4*)(out + LAB_OFF);
    for (int a = tid; a < A_TOTAL; a += 1024) {
        int l, off;
        if (a < 49152)      { l = 0; off = 0; }
        else if (a < 61440) { l = 1; off = 49152; }
        else if (a < 64512) { l = 2; off = 61440; }
        else if (a < 65280) { l = 3; off = 64512; }
        else                { l = 4; off = 65280; }
        const int code = (int)myCodes[a];
        const int mgv = code & 31;
        const int cls = code >> 5;
        int fg = -1;
#pragma unroll
        for (int g = 0; g < NG; ++g)
            if (sforce[g] == a) fg = g;
        const bool pos = (cls == 2) || (fg >= 0);
        const int ug = (fg >= 0) ? fg : mgv;
        myCodes[a] = pos ? sid[ug] : ((cls == 1) ? -1.0f : 0.0f);
        float t0 = 0.f, t1 = 0.f, t2 = 0.f, t3 = 0.f;
        if (pos) {
            const float4 A = ldbox(ans[l], a - off, isbf);
            const float4 G = sbox4[ug];
            reg_transform(A, G.x, G.y, G.z, G.w, t0, t1, t2, t3);
        }
        rp[(size_t)b * A_TOTAL + a] = make_float4(t0, t1, t2, t3);
    }
}

extern "C" void kernel_launch(void* const* d_in, const int* in_sizes, int n_in,
                              void* d_out, int out_size, void* d_ws, size_t ws_size,
                              hipStream_t stream) {
    const void* bb = d_in[0];
    const void* ids = d_in[1];
    const void* an[5] = {d_in[2], d_in[3], d_in[4], d_in[5], d_in[6]};
    if (n_in == 7) {
        for (int i = 0; i < 7; ++i) {
            switch (in_sizes[i]) {
                case 2560:   bb    = d_in[i]; break;
                case 640:    ids   = d_in[i]; break;
                case 196608: an[0] = d_in[i]; break;
                case 49152:  an[1] = d_in[i]; break;
                case 12288:  an[2] = d_in[i]; break;
                case 3072:   an[3] = d_in[i]; break;
                case 768:    an[4] = d_in[i]; break;
                default: break;
            }
        }
    }
    float* out = (float*)d_out;
    const size_t need = (size_t)NSLOT * sizeof(unsigned long long);  // 25600 B

    if (ws_size >= need) {
        unsigned long long* slots = (unsigned long long*)d_ws;
        (void)hipMemsetAsync(d_ws, 0, need, stream);
        hipLaunchKernelGGL(kCodes, dim3(65, NB), dim3(256), 0, stream,
                           bb, ids, an[0], an[1], an[2], an[3], an[4],
                           out, slots);
        hipLaunchKernelGGL(kForce, dim3(NB), dim3(64), 0, stream,
                           bb, ids, an[0], an[1], an[2], an[3], an[4],
                           slots, out);
    } else {
        hipLaunchKernelGGL(kFused, dim3(NB), dim3(1024), 0, stream,
                           bb, ids, an[0], an[1], an[2], an[3], an[4], out);
    }
}